// Round 9
// baseline (162.949 us; speedup 1.0000x reference)
//
#include <hip/hip_runtime.h>
#include <math.h>
#include <stdint.h>

typedef unsigned long long u64;

#define HH 1024
#define WW 1024
#define NB 8
#define WPR 16  // u64 words per image row (1024/64)

// Row-major 3x3 Gaussian, literal reference weights (all powers of 2 -> each
// product is exact; accumulation order matches a row-major conv loop).
__device__ __forceinline__ float blur_at(const float* p) {
#pragma clang fp contract(off)
    float s = p[0] * 0.0625f;
    s += p[1] * 0.125f;
    s += p[2] * 0.0625f;
    s += p[70] * 0.125f;
    s += p[71] * 0.25f;
    s += p[72] * 0.125f;
    s += p[140] * 0.0625f;
    s += p[141] * 0.125f;
    s += p[142] * 0.0625f;
    return s;
}

// Row-major signed accumulation exactly as conv(blurred, SOBEL_X/Y) would,
// skipping the zero-weight taps (sign-of-zero is inconsequential downstream).
__device__ __forceinline__ void sobel_at(const float* p, float& osx, float& osy) {
#pragma clang fp contract(off)
    float x00 = p[0], x01 = p[1], x02 = p[2];
    float x10 = p[68], x12 = p[70];
    float x20 = p[136], x21 = p[137], x22 = p[138];
    float gx = -x00;
    gx += x02;
    gx -= 2.f * x10;
    gx += 2.f * x12;
    gx -= x20;
    gx += x22;
    float gy = -x00;
    gy -= 2.f * x01;
    gy -= x02;
    gy += x20;
    gy += 2.f * x21;
    gy += x22;
    osx = gx;
    osy = gy;
}

// ---------------- Kernel 1: blur + sobel + NMS + double threshold -> bitmaps ----------------
__global__ __launch_bounds__(256) void canny_s1(const float* __restrict__ in,
                                                u64* __restrict__ strongB,
                                                u64* __restrict__ weakB) {
#pragma clang fp contract(off)
    const int bx  = blockIdx.x;
    const int b   = bx >> 8;          // image index
    const int rem = bx & 255;
    const int y0  = (rem >> 4) << 6;  // tile origin
    const int x0  = (rem & 15) << 6;
    const float* img = in + (size_t)b * (HH * WW);

    __shared__ float sIn[70 * 70];    // input tile; later reused as mag (stride 66)
    __shared__ float sBl[68 * 68];    // blurred tile
    float* sMag = sIn;

    const int tid = threadIdx.x;

    // ---- load input tile, zero outside image (matches SAME zero padding) ----
    for (int idx = tid; idx < 70 * 70; idx += 256) {
        int r = idx / 70, c = idx - r * 70;
        int gy = y0 - 3 + r, gx = x0 - 3 + c;
        float v = 0.f;
        if ((unsigned)gy < HH && (unsigned)gx < WW) v = img[gy * WW + gx];
        sIn[idx] = v;
    }
    __syncthreads();

    // ---- Gaussian blur on 68x68 (origin y0-2,x0-2); zero outside image ----
    for (int idx = tid; idx < 68 * 68; idx += 256) {
        int r = idx / 68, c = idx - r * 68;
        int gy = y0 - 2 + r, gx = x0 - 2 + c;
        float v = 0.f;
        if ((unsigned)gy < HH && (unsigned)gx < WW) v = blur_at(&sIn[r * 70 + c]);
        sBl[idx] = v;
    }
    __syncthreads();

    // ---- gradient magnitude on 66x66 (origin y0-1,x0-1) into sMag ----
    for (int idx = tid; idx < 66 * 66; idx += 256) {
        int r = idx / 66, c = idx - r * 66;
        int gy = y0 - 1 + r, gx = x0 - 1 + c;
        float v = 0.f;
        if ((unsigned)gy < HH && (unsigned)gx < WW) {
            float sx, sy;
            sobel_at(&sBl[r * 68 + c], sx, sy);
            float xx = sx * sx;
            float yy = sy * sy;
            v = sqrtf(xx + yy);
        }
        sMag[r * 66 + c] = v;
    }
    __syncthreads();

    // ---- NMS + double threshold; bitpack one image-row word per wave via ballot ----
    const int lane = tid & 63;
    const int wv   = tid >> 6;

    for (int y = wv; y < 64; y += 4) {
        float sx, sy;
        sobel_at(&sBl[(y + 1) * 68 + (lane + 1)], sx, sy);

        const int base = (y + 1) * 66 + (lane + 1);
        float m = sMag[base];

        // Replicate: angle = atan2(gy,gx)*180/pi; if (<0) += 180; bucket compares.
        float ang = (float)atan2((double)sy, (double)sx);
        float deg = ang * 57.29577951308232f;  // f32(180/pi)
        if (deg < 0.f) deg += 180.f;

        float n1, n2;
        if (deg < 22.5f || deg >= 157.5f) {        // b0: left/right
            n1 = sMag[base + 1];      n2 = sMag[base - 1];
        } else if (deg < 67.5f) {                  // b1: 45 deg
            n1 = sMag[base - 66 + 1]; n2 = sMag[base + 66 - 1];
        } else if (deg < 112.5f) {                 // b2: up/down
            n1 = sMag[base - 66];     n2 = sMag[base + 66];
        } else {                                   // b3: 135 deg
            n1 = sMag[base - 66 - 1]; n2 = sMag[base + 66 + 1];
        }

        bool keep = (m >= n1) && (m >= n2);
        bool st = keep && (m >= 0.3f);
        bool wk = keep && (m >= 0.1f) && (m < 0.3f);

        u64 bs = __ballot(st);
        u64 bw = __ballot(wk);
        if (lane == 0) {
            size_t o = (size_t)(b * HH + y0 + y) * WPR + (x0 >> 6);
            strongB[o] = bs;
            weakB[o]   = bw;
        }
    }
}

// ---------------- Kernel 2: bit-parallel hysteresis (16 iters) + float output ----------------
// Block tile 64x64, region = 96 rows x 3 u64 words (halo 16 rows, 64 cols).
__global__ __launch_bounds__(256) void canny_s2(const u64* __restrict__ strongB,
                                                const u64* __restrict__ weakB,
                                                float* __restrict__ out) {
    const int bx  = blockIdx.x;
    const int b   = bx >> 8;
    const int rem = bx & 255;
    const int y0  = (rem >> 4) << 6;
    const int x0  = (rem & 15) << 6;
    const int w0  = (x0 >> 6) - 1;   // leftmost region word column

    __shared__ u64 sE[2][96][3];
    __shared__ u64 sW[96][3];

    const int tid = threadIdx.x;

    for (int idx = tid; idx < 96 * 3; idx += 256) {
        int r = idx / 3, w = idx - r * 3;
        int gy = y0 - 16 + r, gw = w0 + w;
        u64 s = 0, k = 0;
        if ((unsigned)gy < HH && (unsigned)gw < WPR) {
            size_t o = (size_t)(b * HH + gy) * WPR + gw;
            s = strongB[o];
            k = weakB[o];
        }
        sE[0][r][w] = s;
        sW[r][w]    = k;
    }
    __syncthreads();

    for (int it = 0; it < 16; ++it) {
        const u64 (*src)[3] = sE[it & 1];
        u64 (*dst)[3]       = sE[(it & 1) ^ 1];
        for (int idx = tid; idx < 96 * 3; idx += 256) {
            int r = idx / 3, w = idx - r * 3;
            u64 dil = 0;
#pragma unroll
            for (int dr = -1; dr <= 1; ++dr) {
                int rr = r + dr;
                if ((unsigned)rr < 96u) {
                    u64 mid = src[rr][w];
                    u64 lft = (w > 0) ? src[rr][w - 1] : 0ull;
                    u64 rgt = (w < 2) ? src[rr][w + 1] : 0ull;
                    dil |= mid | (mid << 1) | (mid >> 1) | (lft >> 63) | (rgt << 63);
                }
            }
            dst[r][w] = src[r][w] | (sW[r][w] & dil);
        }
        __syncthreads();
    }

    // 16 iterations -> final state is in sE[0]
    const int lane = tid & 63;
    const int wv   = tid >> 6;
    for (int y = wv; y < 64; y += 4) {
        u64 word = sE[0][y + 16][1];
        out[(size_t)(b * HH + y0 + y) * WW + x0 + lane] = ((word >> lane) & 1ull) ? 1.f : 0.f;
    }
}

extern "C" void kernel_launch(void* const* d_in, const int* in_sizes, int n_in,
                              void* d_out, int out_size, void* d_ws, size_t ws_size,
                              hipStream_t stream) {
    const float* in = (const float*)d_in[0];
    float* out = (float*)d_out;

    u64* strongB = (u64*)d_ws;                       // 1 MB
    u64* weakB   = strongB + (size_t)NB * HH * WPR;  // 1 MB

    dim3 grid(NB * 16 * 16);  // 2048 tiles
    canny_s1<<<grid, 256, 0, stream>>>(in, strongB, weakB);
    canny_s2<<<grid, 256, 0, stream>>>(strongB, weakB, out);
}

// Round 10
// 147.396 us; speedup vs baseline: 1.1055x; 1.1055x over previous
//
#include <hip/hip_runtime.h>
#include <math.h>
#include <stdint.h>

typedef unsigned long long u64;

#define HH 1024
#define WW 1024
#define NB 8
#define WPR 16  // u64 words per image row (1024/64)

// Row-major 3x3 Gaussian, literal reference weights (all powers of 2 -> each
// product is exact; accumulation order matches a row-major conv loop).
__device__ __forceinline__ float blur_at(const float* p) {
#pragma clang fp contract(off)
    float s = p[0] * 0.0625f;
    s += p[1] * 0.125f;
    s += p[2] * 0.0625f;
    s += p[70] * 0.125f;
    s += p[71] * 0.25f;
    s += p[72] * 0.125f;
    s += p[140] * 0.0625f;
    s += p[141] * 0.125f;
    s += p[142] * 0.0625f;
    return s;
}

// Row-major signed accumulation exactly as conv(blurred, SOBEL_X/Y) would.
__device__ __forceinline__ void sobel_at(const float* p, float& osx, float& osy) {
#pragma clang fp contract(off)
    float x00 = p[0], x01 = p[1], x02 = p[2];
    float x10 = p[68], x12 = p[70];
    float x20 = p[136], x21 = p[137], x22 = p[138];
    float gx = -x00;
    gx += x02;
    gx -= 2.f * x10;
    gx += 2.f * x12;
    gx -= x20;
    gx += x22;
    float gy = -x00;
    gy -= 2.f * x01;
    gy -= x02;
    gy += x20;
    gy += 2.f * x21;
    gy += x22;
    osx = gx;
    osy = gy;
}

// Exact bucket: bit-identical to the validated reference chain (R9 pass).
__device__ __forceinline__ int bucket_exact(float sy, float sx) {
#pragma clang fp contract(off)
    float ang = (float)atan2((double)sy, (double)sx);
    float deg = ang * 57.29577951308232f;  // f32(180/pi)
    if (deg < 0.f) deg += 180.f;
    if (deg < 22.5f || deg >= 157.5f) return 0;
    if (deg < 67.5f) return 1;
    if (deg < 112.5f) return 2;
    return 3;
}

// ---------------- Kernel 1: blur + sobel + NMS + double threshold -> bitmaps ----------------
__global__ __launch_bounds__(256) void canny_s1(const float* __restrict__ in,
                                                u64* __restrict__ strongB,
                                                u64* __restrict__ weakB) {
#pragma clang fp contract(off)
    const int bx  = blockIdx.x;
    const int b   = bx >> 8;          // image index
    const int rem = bx & 255;
    const int y0  = (rem >> 4) << 6;  // tile origin
    const int x0  = (rem & 15) << 6;
    const float* img = in + (size_t)b * (HH * WW);

    __shared__ float sIn[70 * 70];    // input tile; later reused as mag (stride 66)
    __shared__ float sBl[68 * 68];    // blurred tile
    float* sMag = sIn;

    const int tid = threadIdx.x;

    // ---- load input tile, zero outside image (matches SAME zero padding) ----
    for (int idx = tid; idx < 70 * 70; idx += 256) {
        int r = idx / 70, c = idx - r * 70;
        int gy = y0 - 3 + r, gx = x0 - 3 + c;
        float v = 0.f;
        if ((unsigned)gy < HH && (unsigned)gx < WW) v = img[gy * WW + gx];
        sIn[idx] = v;
    }
    __syncthreads();

    // ---- Gaussian blur on 68x68 (origin y0-2,x0-2); zero outside image ----
    for (int idx = tid; idx < 68 * 68; idx += 256) {
        int r = idx / 68, c = idx - r * 68;
        int gy = y0 - 2 + r, gx = x0 - 2 + c;
        float v = 0.f;
        if ((unsigned)gy < HH && (unsigned)gx < WW) v = blur_at(&sIn[r * 70 + c]);
        sBl[idx] = v;
    }
    __syncthreads();

    // ---- gradient magnitude on 66x66 (origin y0-1,x0-1) into sMag ----
    for (int idx = tid; idx < 66 * 66; idx += 256) {
        int r = idx / 66, c = idx - r * 66;
        int gy = y0 - 1 + r, gx = x0 - 1 + c;
        float v = 0.f;
        if ((unsigned)gy < HH && (unsigned)gx < WW) {
            float sx, sy;
            sobel_at(&sBl[r * 68 + c], sx, sy);
            float xx = sx * sx;
            float yy = sy * sy;
            v = sqrtf(xx + yy);
        }
        sMag[r * 66 + c] = v;
    }
    __syncthreads();

    // ---- NMS + double threshold; bitpack one image-row word per wave via ballot ----
    const int lane = tid & 63;
    const int wv   = tid >> 6;

    for (int y = wv; y < 64; y += 4) {
        float sx, sy;
        sobel_at(&sBl[(y + 1) * 68 + (lane + 1)], sx, sy);

        const int base = (y + 1) * 66 + (lane + 1);
        float m = sMag[base];

        // Guarded classification: cheap tan-ratio test away from bucket
        // boundaries; bit-exact atan2 chain within the guard band.
        // Disagreement band between the two tests is ~1e-6 rad; guard is
        // ~0.7e-4 rad (100x margin). ax=ay=0 falls into the exact path.
        const float t1 = 0.41421356237309503f;  // tan 22.5 deg
        const float t2 = 2.414213562373095f;    // tan 67.5 deg
        float ax = fabsf(sx), ay = fabsf(sy);
        float r1 = t1 * ax, r2 = t2 * ax;
        int bucket;
        bool near1 = fabsf(ay - r1) <= 1e-4f * (ay + r1);
        bool near2 = fabsf(ay - r2) <= 1e-4f * (ay + r2);
        if (near1 | near2) {
            bucket = bucket_exact(sy, sx);
        } else if (ay < r1) {
            bucket = 0;                          // deg in [0,22.5) U [157.5,180)
        } else if (ay < r2) {
            bucket = ((sx > 0.f) == (sy > 0.f)) ? 1 : 3;  // tan>0 -> (22.5,67.5) else (112.5,157.5)
        } else {
            bucket = 2;                          // (67.5,112.5)
        }

        float n1, n2;
        if (bucket == 0)      { n1 = sMag[base + 1];      n2 = sMag[base - 1]; }
        else if (bucket == 1) { n1 = sMag[base - 66 + 1]; n2 = sMag[base + 66 - 1]; }
        else if (bucket == 2) { n1 = sMag[base - 66];     n2 = sMag[base + 66]; }
        else                  { n1 = sMag[base - 66 - 1]; n2 = sMag[base + 66 + 1]; }

        bool keep = (m >= n1) && (m >= n2);
        bool st = keep && (m >= 0.3f);
        bool wk = keep && (m >= 0.1f) && (m < 0.3f);

        u64 bs = __ballot(st);
        u64 bw = __ballot(wk);
        if (lane == 0) {
            size_t o = (size_t)(b * HH + y0 + y) * WPR + (x0 >> 6);
            strongB[o] = bs;
            weakB[o]   = bw;
        }
    }
}

// ---------------- Kernel 2: register+shfl bit-parallel hysteresis ----------------
// One wave per 64x64 tile; lane L holds region rows 2L,2L+1 (96 rows in 48
// lanes) x 3 u64 words in registers. Horizontal dilation = shifts/ORs;
// vertical = 2 shfls per word. No LDS, no barriers (wave-synchronous Jacobi).
__global__ __launch_bounds__(256) void canny_s2(const u64* __restrict__ strongB,
                                                const u64* __restrict__ weakB,
                                                float* __restrict__ out) {
    const int wave = threadIdx.x >> 6;
    const int lane = threadIdx.x & 63;
    const int tile = blockIdx.x * 4 + wave;  // 0..2047
    const int b   = tile >> 8;
    const int rem = tile & 255;
    const int y0  = (rem >> 4) << 6;
    const int x0  = (rem & 15) << 6;
    const int w0  = (x0 >> 6) - 1;   // leftmost region word column

    u64 e[2][3], k[2][3];
#pragma unroll
    for (int i = 0; i < 2; ++i) {
        int rr = 2 * lane + i;
        int gy = y0 - 16 + rr;
#pragma unroll
        for (int w = 0; w < 3; ++w) {
            int gw = w0 + w;
            u64 s = 0, kk = 0;
            if (rr < 96 && (unsigned)gy < HH && (unsigned)gw < WPR) {
                size_t o = (size_t)(b * HH + gy) * WPR + gw;
                s  = strongB[o];
                kk = weakB[o];
            }
            e[i][w] = s;
            k[i][w] = kk;
        }
    }

    for (int it = 0; it < 16; ++it) {
        u64 hd[2][3];
#pragma unroll
        for (int i = 0; i < 2; ++i)
#pragma unroll
            for (int w = 0; w < 3; ++w) {
                u64 m = e[i][w];
                u64 l = (w > 0) ? e[i][w - 1] : 0ull;
                u64 r = (w < 2) ? e[i][w + 1] : 0ull;
                hd[i][w] = m | (m << 1) | (m >> 1) | (l >> 63) | (r << 63);
            }
#pragma unroll
        for (int w = 0; w < 3; ++w) {
            u64 up = (u64)__shfl_up((long long)hd[1][w], 1);    // lane L-1 row 2L-1
            if (lane == 0) up = 0ull;
            u64 dn = (u64)__shfl_down((long long)hd[0][w], 1);  // lane L+1 row 2L+2
            if (lane == 63) dn = 0ull;
            u64 d0 = up | hd[0][w] | hd[1][w];
            u64 d1 = hd[0][w] | hd[1][w] | dn;
            e[0][w] |= k[0][w] & d0;
            e[1][w] |= k[1][w] & d1;
        }
    }

    // store tile rows (region rows 16..79 -> lanes 8..39), mid word only
    if (lane >= 8 && lane < 40) {
#pragma unroll
        for (int i = 0; i < 2; ++i) {
            int gy = y0 - 16 + 2 * lane + i;
            u64 word = e[i][1];
            float* orow = out + (size_t)(b * HH + gy) * WW + x0;
            for (int c = 0; c < 64; c += 4) {
                float4 v;
                v.x = ((word >> c) & 1ull)       ? 1.f : 0.f;
                v.y = ((word >> (c + 1)) & 1ull) ? 1.f : 0.f;
                v.z = ((word >> (c + 2)) & 1ull) ? 1.f : 0.f;
                v.w = ((word >> (c + 3)) & 1ull) ? 1.f : 0.f;
                *reinterpret_cast<float4*>(orow + c) = v;
            }
        }
    }
}

extern "C" void kernel_launch(void* const* d_in, const int* in_sizes, int n_in,
                              void* d_out, int out_size, void* d_ws, size_t ws_size,
                              hipStream_t stream) {
    const float* in = (const float*)d_in[0];
    float* out = (float*)d_out;

    u64* strongB = (u64*)d_ws;                       // 1 MB
    u64* weakB   = strongB + (size_t)NB * HH * WPR;  // 1 MB

    canny_s1<<<dim3(NB * 16 * 16), 256, 0, stream>>>(in, strongB, weakB);
    canny_s2<<<dim3(NB * 16 * 16 / 4), 256, 0, stream>>>(strongB, weakB, out);
}